// Round 1
// baseline (1348.310 us; speedup 1.0000x reference)
//
#include <hip/hip_runtime.h>
#include <hip/hip_bf16.h>

#define DEV static __device__ __forceinline__

typedef __attribute__((ext_vector_type(8))) short bfx8;
typedef __attribute__((ext_vector_type(4))) float f32x4;
typedef __attribute__((ext_vector_type(4))) unsigned short us4;

DEV unsigned short f2bf(float f){
  unsigned u = __builtin_bit_cast(unsigned, f);
  u += 0x7fffu + ((u >> 16) & 1u);
  return (unsigned short)(u >> 16);
}
DEV float bf2f(unsigned short h){
  unsigned u = ((unsigned)h) << 16;
  return __builtin_bit_cast(float, u);
}
DEV void gld16(const void* g, void* l){
  __builtin_amdgcn_global_load_lds((const __attribute__((address_space(1))) void*)g,
                                   (__attribute__((address_space(3))) void*)l, 16, 0, 0);
}
DEV f32x4 mfma16(bfx8 a, bfx8 b, f32x4 c){
  return __builtin_amdgcn_mfma_f32_16x16x32_bf16(a, b, c, 0, 0, 0);
}

// ---------------------------------------------------------------- weights ----
// Transpose+convert all fp32 weights to bf16 B^T ([N][K]) layouts.
// z: 0..47 attn_w [l][br][p][512][512]; 48..51 ff_w1; 52..55 ff_w2; 56 out1; 57 out2
__global__ __launch_bounds__(256, 2)
void wconv_kernel(const float* __restrict__ attn_w, const float* __restrict__ ff_w1,
                  const float* __restrict__ ff_w2, const float* __restrict__ out1_w,
                  const float* __restrict__ out2_w,
                  unsigned short* __restrict__ bqkv, unsigned short* __restrict__ bout,
                  unsigned short* __restrict__ bff1, unsigned short* __restrict__ bff2,
                  unsigned short* __restrict__ bo1, unsigned short* __restrict__ bo2)
{
  __shared__ float ts[64][65];
  const int z = blockIdx.z;
  const float* src; unsigned short* dst; int K, N, stride;
  if (z < 48){
    int l = z / 12, br = (z % 12) >> 2, p = z & 3;
    src = attn_w + (size_t)z * 262144; K = 512; N = 512;
    if (p < 3){ dst = bqkv + (size_t)l * 4608 * 512 + (size_t)(br * 3 + p) * 262144; stride = 512; }
    else      { dst = bout + (size_t)l * 512 * 1536 + (size_t)br * 512;              stride = 1536; }
  } else if (z < 52){
    int l = z - 48; src = ff_w1 + (size_t)l * 524288; K = 512; N = 1024;
    dst = bff1 + (size_t)l * 524288; stride = 512;
  } else if (z < 56){
    int l = z - 52; src = ff_w2 + (size_t)l * 524288; K = 1024; N = 512;
    dst = bff2 + (size_t)l * 524288; stride = 1024;
  } else if (z == 56){
    src = out1_w; K = 512; N = 512; dst = bo1; stride = 512;
  } else {
    src = out2_w; K = 512; N = 256; dst = bo2; stride = 512;
  }
  const int n0 = blockIdx.x << 6, k0 = blockIdx.y << 6;
  if (n0 >= N || k0 >= K) return;
  const int tx = threadIdx.x & 63, ty = threadIdx.x >> 6;
  #pragma unroll
  for (int i = 0; i < 16; ++i){
    int row = (ty << 4) + i;
    ts[row][tx] = src[(size_t)(k0 + row) * N + n0 + tx];
  }
  __syncthreads();
  #pragma unroll
  for (int i = 0; i < 16; ++i){
    int row = (ty << 4) + i;
    dst[(size_t)(n0 + row) * stride + k0 + tx] = f2bf(ts[tx][row]);
  }
}

// ---------------------------------------------------------------- embed ------
__global__ __launch_bounds__(256, 4)
void embed_kernel(const float* __restrict__ x, const float* __restrict__ cond,
                  const float* __restrict__ in_w, const float* __restrict__ in_b,
                  const float* __restrict__ cond_w, const float* __restrict__ cond_b,
                  float* __restrict__ h)
{
  __shared__ float xs[18];
  __shared__ float cs[89];
  const int m = blockIdx.x;
  const int tid = threadIdx.x;
  if (tid < 18) xs[tid] = x[(size_t)m * 18 + tid];
  if (tid >= 32 && tid < 121) cs[tid - 32] = cond[(size_t)m * 89 + (tid - 32)];
  __syncthreads();
  #pragma unroll
  for (int hf = 0; hf < 2; ++hf){
    const int c = tid + (hf << 8);
    float a = in_b[c] + cond_b[c];
    #pragma unroll
    for (int k = 0; k < 18; ++k) a += xs[k] * in_w[k * 512 + c];
    for (int k = 0; k < 89; ++k) a += cs[k] * cond_w[k * 512 + c];
    h[(size_t)m * 512 + c] = a;
  }
}

// ---------------------------------------------------------------- inorm ------
// per-token InstanceNorm over D=512 (population var), fp32 in -> bf16 out
__global__ __launch_bounds__(256, 4)
void inorm_kernel(const float* __restrict__ in, unsigned short* __restrict__ ob)
{
  const int wid = (blockIdx.x << 2) + (threadIdx.x >> 6);
  const int lane = threadIdx.x & 63;
  const float* row = in + (size_t)wid * 512;
  const float4 v0 = *(const float4*)(row + (lane << 2));
  const float4 v1 = *(const float4*)(row + 256 + (lane << 2));
  float s = v0.x + v0.y + v0.z + v0.w + v1.x + v1.y + v1.z + v1.w;
  float q = v0.x*v0.x + v0.y*v0.y + v0.z*v0.z + v0.w*v0.w
          + v1.x*v1.x + v1.y*v1.y + v1.z*v1.z + v1.w*v1.w;
  #pragma unroll
  for (int sh = 1; sh < 64; sh <<= 1){
    s += __shfl_xor(s, sh, 64);
    q += __shfl_xor(q, sh, 64);
  }
  const float mean = s * (1.f / 512.f);
  const float var = q * (1.f / 512.f) - mean * mean;
  const float rs = rsqrtf(var + 1e-5f);
  us4 o0, o1;
  o0[0] = f2bf((v0.x - mean) * rs); o0[1] = f2bf((v0.y - mean) * rs);
  o0[2] = f2bf((v0.z - mean) * rs); o0[3] = f2bf((v0.w - mean) * rs);
  o1[0] = f2bf((v1.x - mean) * rs); o1[1] = f2bf((v1.y - mean) * rs);
  o1[2] = f2bf((v1.z - mean) * rs); o1[3] = f2bf((v1.w - mean) * rs);
  *(us4*)(ob + (size_t)wid * 512 + (lane << 2)) = o0;
  *(us4*)(ob + (size_t)wid * 512 + 256 + (lane << 2)) = o1;
}

// plain fp32 -> bf16
__global__ void f2b_kernel(const float* __restrict__ in, unsigned short* __restrict__ ob, int n)
{
  const int i = (blockIdx.x * 256 + threadIdx.x) << 2;
  if (i >= n) return;
  const float4 v = *(const float4*)(in + i);
  us4 o; o[0] = f2bf(v.x); o[1] = f2bf(v.y); o[2] = f2bf(v.z); o[3] = f2bf(v.w);
  *(us4*)(ob + i) = o;
}

// ---------------------------------------------------------------- GEMM -------
// C = A[M][K] * B^T  with B stored [N][K], bf16 in, fp32 acc. 128x128 tile,
// BK=64, 4 waves (2x2 of 64x64), m97-style global_load_lds staging.
// MODE 1: Cb = bf16(relu(acc+bias))   MODE 2: Cf += acc+bias
// MODE 3: QKV scatter: q/k standard [br][p][8192][512]; v transposed [br][b][h][dk][s]
template<int MODE>
__global__ __launch_bounds__(256, 2)
void gemm_bt(const unsigned short* __restrict__ A, const unsigned short* __restrict__ B,
             const float* __restrict__ bias, float* __restrict__ Cf,
             unsigned short* __restrict__ Cb, unsigned short* __restrict__ qkp,
             unsigned short* __restrict__ vtp, int M, int N, int K)
{
  __shared__ unsigned short As[128 * 64];
  __shared__ unsigned short Bs[128 * 64];
  const int tid = threadIdx.x;
  const int w = tid >> 6, lane = tid & 63;
  const int wm = w >> 1, wn = w & 1;
  const int lr = lane & 15, lh = lane >> 4;
  const int m0 = blockIdx.x << 7, n0 = blockIdx.y << 7;
  const int rA = lane >> 3;             // 0..7 row within a wave's 8-row chunk
  const int cA = (lane & 7) << 3;       // elem offset within row (16B granules)

  f32x4 acc[4][4];
  #pragma unroll
  for (int i = 0; i < 4; ++i)
    #pragma unroll
    for (int j = 0; j < 4; ++j) acc[i][j] = (f32x4)0.f;

  const int nkt = K >> 6;
  auto stage = [&](int kt){
    #pragma unroll
    for (int c = 0; c < 4; ++c){
      const int r = (c << 5) + (w << 3) + rA;
      gld16(A + (size_t)(m0 + r) * K + (kt << 6) + cA,
            (char*)As + ((c << 5) + (w << 3)) * 128);
      gld16(B + (size_t)(n0 + r) * K + (kt << 6) + cA,
            (char*)Bs + ((c << 5) + (w << 3)) * 128);
    }
  };
  stage(0);
  for (int kt = 0; kt < nkt; ++kt){
    __syncthreads();
    #pragma unroll
    for (int kk = 0; kk < 2; ++kk){
      bfx8 af[4], bg[4];
      #pragma unroll
      for (int i = 0; i < 4; ++i)
        af[i] = *(const bfx8*)(As + ((wm << 6) + (i << 4) + lr) * 64 + (kk << 5) + (lh << 3));
      #pragma unroll
      for (int j = 0; j < 4; ++j)
        bg[j] = *(const bfx8*)(Bs + ((wn << 6) + (j << 4) + lr) * 64 + (kk << 5) + (lh << 3));
      #pragma unroll
      for (int i = 0; i < 4; ++i)
        #pragma unroll
        for (int j = 0; j < 4; ++j)
          acc[i][j] = mfma16(af[i], bg[j], acc[i][j]);
    }
    __syncthreads();
    if (kt + 1 < nkt) stage(kt + 1);
  }
  #pragma unroll
  for (int i = 0; i < 4; ++i){
    const int row = m0 + (wm << 6) + (i << 4) + (lh << 2);
    #pragma unroll
    for (int j = 0; j < 4; ++j){
      const int col = n0 + (wn << 6) + (j << 4) + lr;
      if constexpr (MODE == 1){
        const float bv = bias ? bias[col] : 0.f;
        #pragma unroll
        for (int r = 0; r < 4; ++r){
          float v = acc[i][j][r] + bv;
          v = fmaxf(v, 0.f);
          Cb[(size_t)(row + r) * N + col] = f2bf(v);
        }
      } else if constexpr (MODE == 2){
        const float bv = bias ? bias[col] : 0.f;
        #pragma unroll
        for (int r = 0; r < 4; ++r){
          const size_t idx = (size_t)(row + r) * N + col;
          Cf[idx] += acc[i][j][r] + bv;
        }
      } else {
        const int br = col / 1536;
        const int rem = col - br * 1536;
        const int p = rem >> 9;
        const int c = rem & 511;
        const float bv = bias ? bias[(size_t)((br << 2) + p) * 512 + c] : 0.f;
        if (p < 2){
          #pragma unroll
          for (int r = 0; r < 4; ++r)
            qkp[((size_t)((br << 1) + p) * 8192 + row + r) * 512 + c] = f2bf(acc[i][j][r] + bv);
        } else {
          const int b_ = row >> 9, s0 = row & 511;
          const int hi = c >> 7, dk = c & 127;
          us4 pk;
          #pragma unroll
          for (int r = 0; r < 4; ++r) pk[r] = f2bf(acc[i][j][r] + bv);
          *(us4*)(vtp + (((size_t)(br * 16 + b_) * 4 + hi) * 128 + dk) * 512 + s0) = pk;
        }
      }
    }
  }
}

// ---------------------------------------------------------------- attention --
// grid (8 qtiles, 64 bh, 3 branches); 4 waves; wave owns 16 q-rows.
// Full 512-wide score row kept in registers; softmax wave-parallel; P goes
// through XOR-swizzled LDS to re-layout as PV's A operand.
__global__ __launch_bounds__(256, 2)
void attn_kernel(const unsigned short* __restrict__ qk, const unsigned short* __restrict__ vt,
                 const int* __restrict__ mask0, const int* __restrict__ mask1,
                 const int* __restrict__ mask2, unsigned short* __restrict__ outp)
{
  __shared__ unsigned short Pl[4 * 16 * 512];  // 64KB
  __shared__ unsigned short Ks[32 * 128];      // 8KB
  __shared__ unsigned short Vs[128 * 32];      // 8KB
  const int tid = threadIdx.x;
  const int w = tid >> 6, lane = tid & 63;
  const int lr = lane & 15, lh = lane >> 4;
  const int qt = blockIdx.x, bh = blockIdx.y, br = blockIdx.z;
  const int b = bh >> 2, h = bh & 3;
  const int q0 = (qt << 6) + (w << 4);
  const int* mask = (br == 0) ? mask0 : ((br == 1) ? mask1 : mask2);
  const int* mrow = mask + (size_t)b * 512 * 512;

  const unsigned short* qbase = qk + ((size_t)(br * 2 + 0) * 8192 + (size_t)b * 512) * 512 + h * 128;
  const unsigned short* kbase = qk + ((size_t)(br * 2 + 1) * 8192 + (size_t)b * 512) * 512 + h * 128;
  const unsigned short* vbase = vt + ((size_t)(br * 16 + b) * 4 + h) * 128 * 512;

  bfx8 aq[4];
  #pragma unroll
  for (int t = 0; t < 4; ++t)
    aq[t] = *(const bfx8*)(qbase + (size_t)(q0 + lr) * 512 + (t << 5) + (lh << 3));

  f32x4 sc[16][2];
  const float scale = 0.08838834764831845f;  // 1/sqrt(128)

  const int krow = (w << 2) + (lane >> 4);   // K staging: 16 rows / 4KB call
  const int kcol = (lane & 15) << 3;
  const int vrow = (w << 4) + (lane >> 2);   // V staging: 64 rows / 4KB call
  const int vcol = (lane & 3) << 3;

  // phase 1: scores = QK^T, masked+scaled, kept in registers
  #pragma unroll
  for (int kt = 0; kt < 16; ++kt){
    __syncthreads();
    #pragma unroll
    for (int c2 = 0; c2 < 2; ++c2){
      gld16(kbase + (size_t)((kt << 5) + (c2 << 4) + krow) * 512 + kcol,
            (char*)Ks + ((c2 << 4) + (w << 2)) * 256);
    }
    __syncthreads();
    #pragma unroll
    for (int j = 0; j < 2; ++j){
      f32x4 a2 = (f32x4)0.f;
      #pragma unroll
      for (int t = 0; t < 4; ++t){
        bfx8 bk = *(const bfx8*)(Ks + ((j << 4) + lr) * 128 + (t << 5) + (lh << 3));
        a2 = mfma16(aq[t], bk, a2);
      }
      #pragma unroll
      for (int r = 0; r < 4; ++r){
        const int q = q0 + (lh << 2) + r;
        const int kcl = (kt << 5) + (j << 4) + lr;
        const int mv = mrow[(size_t)q * 512 + kcl];
        sc[kt][j][r] = mv ? -1e9f : a2[r] * scale;
      }
    }
  }

  // phase 2: wave-parallel softmax (rows split across regs + 16-lane groups)
  float mx[4] = {-3e38f, -3e38f, -3e38f, -3e38f};
  #pragma unroll
  for (int kt = 0; kt < 16; ++kt)
    #pragma unroll
    for (int j = 0; j < 2; ++j)
      #pragma unroll
      for (int r = 0; r < 4; ++r) mx[r] = fmaxf(mx[r], sc[kt][j][r]);
  #pragma unroll
  for (int s = 1; s < 16; s <<= 1)
    #pragma unroll
    for (int r = 0; r < 4; ++r) mx[r] = fmaxf(mx[r], __shfl_xor(mx[r], s, 64));
  float sm[4] = {0.f, 0.f, 0.f, 0.f};
  unsigned short* pw = Pl + (w << 13);
  #pragma unroll
  for (int kt = 0; kt < 16; ++kt)
    #pragma unroll
    for (int j = 0; j < 2; ++j)
      #pragma unroll
      for (int r = 0; r < 4; ++r){
        const int q = (lh << 2) + r;
        const int kcl = (kt << 5) + (j << 4) + lr;
        const float pv = __expf(sc[kt][j][r] - mx[r]);
        sm[r] += pv;
        pw[(q << 9) + (kcl ^ ((q & 7) << 3))] = f2bf(pv);  // swizzled P store
      }
  #pragma unroll
  for (int s = 1; s < 16; s <<= 1)
    #pragma unroll
    for (int r = 0; r < 4; ++r) sm[r] += __shfl_xor(sm[r], s, 64);
  float linv[4];
  #pragma unroll
  for (int r = 0; r < 4; ++r) linv[r] = 1.f / sm[r];

  // phase 3: O = P * V  (V^T staged to LDS; P read back swizzled as A-frags)
  f32x4 ao[8];
  #pragma unroll
  for (int j = 0; j < 8; ++j) ao[j] = (f32x4)0.f;
  #pragma unroll
  for (int kt = 0; kt < 16; ++kt){
    __syncthreads();
    #pragma unroll
    for (int c2 = 0; c2 < 2; ++c2){
      gld16(vbase + (size_t)((c2 << 6) + vrow) * 512 + (kt << 5) + vcol,
            (char*)Vs + ((c2 << 6) + (w << 4)) * 64);
    }
    __syncthreads();
    bfx8 pa = *(const bfx8*)(pw + (lr << 9) + (((kt << 5) + (lh << 3)) ^ ((lr & 7) << 3)));
    #pragma unroll
    for (int j = 0; j < 8; ++j){
      bfx8 bv = *(const bfx8*)(Vs + ((j << 4) + lr) * 32 + (lh << 3));
      ao[j] = mfma16(pa, bv, ao[j]);
    }
  }
  const size_t obase = (size_t)(b * 512) * 1536 + br * 512 + h * 128;
  #pragma unroll
  for (int j = 0; j < 8; ++j){
    const int d = (j << 4) + lr;
    #pragma unroll
    for (int r = 0; r < 4; ++r){
      const int q = q0 + (lh << 2) + r;
      outp[obase + (size_t)q * 1536 + d] = f2bf(ao[j][r] * linv[r]);
    }
  }
}

// ---------------------------------------------------------------- out3 -------
__global__ __launch_bounds__(256, 4)
void out3_kernel(const unsigned short* __restrict__ t2, const float* __restrict__ w,
                 const float* __restrict__ b2, float* __restrict__ outp)
{
  const int row = (blockIdx.x << 2) + (threadIdx.x >> 6);
  const int lane = threadIdx.x & 63;
  const unsigned short* rp = t2 + (size_t)row * 256 + (lane << 2);
  float a0 = 0.f, a1 = 0.f;
  #pragma unroll
  for (int k = 0; k < 4; ++k){
    const float v = bf2f(rp[k]);
    const int kk = (lane << 2) + k;
    a0 += v * w[kk * 2 + 0];
    a1 += v * w[kk * 2 + 1];
  }
  #pragma unroll
  for (int s = 1; s < 64; s <<= 1){
    a0 += __shfl_xor(a0, s, 64);
    a1 += __shfl_xor(a1, s, 64);
  }
  if (lane == 0){
    outp[(size_t)row * 2 + 0] = a0 + b2[0];
    outp[(size_t)row * 2 + 1] = a1 + b2[1];
  }
}

// ---------------------------------------------------------------- launch -----
extern "C" void kernel_launch(void* const* d_in, const int* in_sizes, int n_in,
                              void* d_out, int out_size, void* d_ws, size_t ws_size,
                              hipStream_t stream)
{
  const float* x      = (const float*)d_in[0];
  const float* cond   = (const float*)d_in[1];
  const int*   mdoor  = (const int*)d_in[2];
  const int*   mself  = (const int*)d_in[3];
  const int*   mgen   = (const int*)d_in[4];
  const float* attn_w = (const float*)d_in[5];
  const float* attn_b = (const float*)d_in[6];
  const float* ff_w1  = (const float*)d_in[7];
  const float* ff_b1  = (const float*)d_in[8];
  const float* ff_w2  = (const float*)d_in[9];
  const float* ff_b2  = (const float*)d_in[10];
  const float* in_w   = (const float*)d_in[11];
  const float* in_b   = (const float*)d_in[12];
  const float* cond_w = (const float*)d_in[13];
  const float* cond_b = (const float*)d_in[14];
  const float* out1_w = (const float*)d_in[15];
  const float* out1_b = (const float*)d_in[16];
  const float* out2_w = (const float*)d_in[17];
  const float* out2_b = (const float*)d_in[18];
  const float* out3_w = (const float*)d_in[19];
  const float* out3_b = (const float*)d_in[20];

  char* p = (char*)d_ws;
  auto carve = [&](size_t bytes) -> char* {
    char* r = p; p += (bytes + 255) & ~(size_t)255; return r;
  };
  float*          h    = (float*)carve(8192ull * 512 * 4);
  unsigned short* h2   = (unsigned short*)carve(8192ull * 512 * 2);
  unsigned short* bqkv = (unsigned short*)carve(4ull * 4608 * 512 * 2);
  unsigned short* bout = (unsigned short*)carve(4ull * 512 * 1536 * 2);
  unsigned short* bff1 = (unsigned short*)carve(4ull * 1024 * 512 * 2);
  unsigned short* bff2 = (unsigned short*)carve(4ull * 512 * 1024 * 2);
  unsigned short* bo1  = (unsigned short*)carve(512ull * 512 * 2);
  unsigned short* bo2  = (unsigned short*)carve(256ull * 512 * 2);
  unsigned short* qkb  = (unsigned short*)carve(6ull * 8192 * 512 * 2);
  unsigned short* vtb  = (unsigned short*)carve(3ull * 16 * 4 * 128 * 512 * 2);
  unsigned short* att  = (unsigned short*)carve(8192ull * 1536 * 2);
  unsigned short* t    = (unsigned short*)carve(8192ull * 1024 * 2);
  unsigned short* t2   = (unsigned short*)carve(8192ull * 256 * 2);
  float* outf = (float*)d_out;

  wconv_kernel<<<dim3(16, 16, 58), 256, 0, stream>>>(attn_w, ff_w1, ff_w2, out1_w, out2_w,
                                                     bqkv, bout, bff1, bff2, bo1, bo2);
  embed_kernel<<<dim3(8192), 256, 0, stream>>>(x, cond, in_w, in_b, cond_w, cond_b, h);
  for (int l = 0; l < 4; ++l){
    inorm_kernel<<<dim3(2048), 256, 0, stream>>>(h, h2);
    gemm_bt<3><<<dim3(64, 36), 256, 0, stream>>>(h2, bqkv + (size_t)l * 4608 * 512,
        attn_b + (size_t)l * 6144, nullptr, nullptr, qkb, vtb, 8192, 4608, 512);
    attn_kernel<<<dim3(8, 64, 3), 256, 0, stream>>>(qkb, vtb, mdoor, mself, mgen, att);
    gemm_bt<2><<<dim3(64, 4), 256, 0, stream>>>(att, bout + (size_t)l * 512 * 1536,
        nullptr, h, nullptr, nullptr, nullptr, 8192, 512, 1536);
    inorm_kernel<<<dim3(2048), 256, 0, stream>>>(h, h2);
    gemm_bt<1><<<dim3(64, 8), 256, 0, stream>>>(h2, bff1 + (size_t)l * 1024 * 512,
        ff_b1 + (size_t)l * 1024, nullptr, t, nullptr, nullptr, 8192, 1024, 512);
    gemm_bt<2><<<dim3(64, 4), 256, 0, stream>>>(t, bff2 + (size_t)l * 512 * 1024,
        ff_b2 + (size_t)l * 512, h, nullptr, nullptr, nullptr, 8192, 512, 1024);
  }
  f2b_kernel<<<dim3(4096), 256, 0, stream>>>(h, h2, 8192 * 512);
  gemm_bt<1><<<dim3(64, 4), 256, 0, stream>>>(h2, bo1, out1_b, nullptr, att, nullptr, nullptr, 8192, 512, 512);
  gemm_bt<1><<<dim3(64, 2), 256, 0, stream>>>(att, bo2, out2_b, nullptr, t2, nullptr, nullptr, 8192, 256, 512);
  out3_kernel<<<dim3(2048), 256, 0, stream>>>(t2, out3_w, out3_b, outf);
}

// Round 2
// 1298.181 us; speedup vs baseline: 1.0386x; 1.0386x over previous
//
#include <hip/hip_runtime.h>
#include <hip/hip_bf16.h>

#define DEV static __device__ __forceinline__

typedef __attribute__((ext_vector_type(8))) short bfx8;
typedef __attribute__((ext_vector_type(4))) float f32x4;
typedef __attribute__((ext_vector_type(4))) unsigned short us4;

DEV unsigned short f2bf(float f){
  unsigned u = __builtin_bit_cast(unsigned, f);
  u += 0x7fffu + ((u >> 16) & 1u);
  return (unsigned short)(u >> 16);
}
DEV float bf2f(unsigned short h){
  unsigned u = ((unsigned)h) << 16;
  return __builtin_bit_cast(float, u);
}
DEV void gld16(const void* g, void* l){
  __builtin_amdgcn_global_load_lds((const __attribute__((address_space(1))) void*)g,
                                   (__attribute__((address_space(3))) void*)l, 16, 0, 0);
}
DEV f32x4 mfma16(bfx8 a, bfx8 b, f32x4 c){
  return __builtin_amdgcn_mfma_f32_16x16x32_bf16(a, b, c, 0, 0, 0);
}

// ---------------------------------------------------------------- weights ----
// Transpose+convert all fp32 weights to bf16 B^T ([N][K]) layouts.
// z: 0..47 attn_w [l][br][p][512][512]; 48..51 ff_w1; 52..55 ff_w2; 56 out1; 57 out2
__global__ __launch_bounds__(256, 2)
void wconv_kernel(const float* __restrict__ attn_w, const float* __restrict__ ff_w1,
                  const float* __restrict__ ff_w2, const float* __restrict__ out1_w,
                  const float* __restrict__ out2_w,
                  unsigned short* __restrict__ bqkv, unsigned short* __restrict__ bout,
                  unsigned short* __restrict__ bff1, unsigned short* __restrict__ bff2,
                  unsigned short* __restrict__ bo1, unsigned short* __restrict__ bo2)
{
  __shared__ float ts[64][65];
  const int z = blockIdx.z;
  const float* src; unsigned short* dst; int K, N, stride;
  if (z < 48){
    int l = z / 12, br = (z % 12) >> 2, p = z & 3;
    src = attn_w + (size_t)z * 262144; K = 512; N = 512;
    if (p < 3){ dst = bqkv + (size_t)l * 4608 * 512 + (size_t)(br * 3 + p) * 262144; stride = 512; }
    else      { dst = bout + (size_t)l * 512 * 1536 + (size_t)br * 512;              stride = 1536; }
  } else if (z < 52){
    int l = z - 48; src = ff_w1 + (size_t)l * 524288; K = 512; N = 1024;
    dst = bff1 + (size_t)l * 524288; stride = 512;
  } else if (z < 56){
    int l = z - 52; src = ff_w2 + (size_t)l * 524288; K = 1024; N = 512;
    dst = bff2 + (size_t)l * 524288; stride = 1024;
  } else if (z == 56){
    src = out1_w; K = 512; N = 512; dst = bo1; stride = 512;
  } else {
    src = out2_w; K = 512; N = 256; dst = bo2; stride = 512;
  }
  const int n0 = blockIdx.x << 6, k0 = blockIdx.y << 6;
  if (n0 >= N || k0 >= K) return;
  const int tx = threadIdx.x & 63, ty = threadIdx.x >> 6;
  #pragma unroll
  for (int i = 0; i < 16; ++i){
    int row = (ty << 4) + i;
    ts[row][tx] = src[(size_t)(k0 + row) * N + n0 + tx];
  }
  __syncthreads();
  #pragma unroll
  for (int i = 0; i < 16; ++i){
    int row = (ty << 4) + i;
    dst[(size_t)(n0 + row) * stride + k0 + tx] = f2bf(ts[tx][row]);
  }
}

// ---------------------------------------------------------------- mask pack --
// int32 {0,1} masks -> bitpack. row = br*8192 + b*512 + q; 8 x u64 per row.
__global__ __launch_bounds__(256, 4)
void mpack_kernel(const int* __restrict__ m0, const int* __restrict__ m1,
                  const int* __restrict__ m2, unsigned long long* __restrict__ mp)
{
  const int row = (blockIdx.x << 2) + (threadIdx.x >> 6);
  const int lane = threadIdx.x & 63;
  const int* src = (row < 8192) ? (m0 + (size_t)row * 512)
                 : (row < 16384 ? (m1 + (size_t)(row - 8192) * 512)
                                : (m2 + (size_t)(row - 16384) * 512));
  #pragma unroll
  for (int c = 0; c < 8; ++c){
    const int v = src[(c << 6) + lane];
    const unsigned long long b = __ballot(v != 0);
    if (lane == c) mp[(size_t)row * 8 + c] = b;
  }
}

// ---------------------------------------------------------------- embed ------
__global__ __launch_bounds__(256, 4)
void embed_kernel(const float* __restrict__ x, const float* __restrict__ cond,
                  const float* __restrict__ in_w, const float* __restrict__ in_b,
                  const float* __restrict__ cond_w, const float* __restrict__ cond_b,
                  float* __restrict__ h)
{
  __shared__ float xs[18];
  __shared__ float cs[89];
  const int m = blockIdx.x;
  const int tid = threadIdx.x;
  if (tid < 18) xs[tid] = x[(size_t)m * 18 + tid];
  if (tid >= 32 && tid < 121) cs[tid - 32] = cond[(size_t)m * 89 + (tid - 32)];
  __syncthreads();
  #pragma unroll
  for (int hf = 0; hf < 2; ++hf){
    const int c = tid + (hf << 8);
    float a = in_b[c] + cond_b[c];
    #pragma unroll
    for (int k = 0; k < 18; ++k) a += xs[k] * in_w[k * 512 + c];
    for (int k = 0; k < 89; ++k) a += cs[k] * cond_w[k * 512 + c];
    h[(size_t)m * 512 + c] = a;
  }
}

// ---------------------------------------------------------------- inorm ------
__global__ __launch_bounds__(256, 4)
void inorm_kernel(const float* __restrict__ in, unsigned short* __restrict__ ob)
{
  const int wid = (blockIdx.x << 2) + (threadIdx.x >> 6);
  const int lane = threadIdx.x & 63;
  const float* row = in + (size_t)wid * 512;
  const float4 v0 = *(const float4*)(row + (lane << 2));
  const float4 v1 = *(const float4*)(row + 256 + (lane << 2));
  float s = v0.x + v0.y + v0.z + v0.w + v1.x + v1.y + v1.z + v1.w;
  float q = v0.x*v0.x + v0.y*v0.y + v0.z*v0.z + v0.w*v0.w
          + v1.x*v1.x + v1.y*v1.y + v1.z*v1.z + v1.w*v1.w;
  #pragma unroll
  for (int sh = 1; sh < 64; sh <<= 1){
    s += __shfl_xor(s, sh, 64);
    q += __shfl_xor(q, sh, 64);
  }
  const float mean = s * (1.f / 512.f);
  const float var = q * (1.f / 512.f) - mean * mean;
  const float rs = rsqrtf(var + 1e-5f);
  us4 o0, o1;
  o0[0] = f2bf((v0.x - mean) * rs); o0[1] = f2bf((v0.y - mean) * rs);
  o0[2] = f2bf((v0.z - mean) * rs); o0[3] = f2bf((v0.w - mean) * rs);
  o1[0] = f2bf((v1.x - mean) * rs); o1[1] = f2bf((v1.y - mean) * rs);
  o1[2] = f2bf((v1.z - mean) * rs); o1[3] = f2bf((v1.w - mean) * rs);
  *(us4*)(ob + (size_t)wid * 512 + (lane << 2)) = o0;
  *(us4*)(ob + (size_t)wid * 512 + 256 + (lane << 2)) = o1;
}

__global__ void f2b_kernel(const float* __restrict__ in, unsigned short* __restrict__ ob, int n)
{
  const int i = (blockIdx.x * 256 + threadIdx.x) << 2;
  if (i >= n) return;
  const float4 v = *(const float4*)(in + i);
  us4 o; o[0] = f2bf(v.x); o[1] = f2bf(v.y); o[2] = f2bf(v.z); o[3] = f2bf(v.w);
  *(us4*)(ob + i) = o;
}

// ---------------------------------------------------------------- GEMM -------
template<int MODE>
__global__ __launch_bounds__(256, 2)
void gemm_bt(const unsigned short* __restrict__ A, const unsigned short* __restrict__ B,
             const float* __restrict__ bias, float* __restrict__ Cf,
             unsigned short* __restrict__ Cb, unsigned short* __restrict__ qkp,
             unsigned short* __restrict__ vtp, int M, int N, int K)
{
  __shared__ unsigned short As[128 * 64];
  __shared__ unsigned short Bs[128 * 64];
  const int tid = threadIdx.x;
  const int w = tid >> 6, lane = tid & 63;
  const int wm = w >> 1, wn = w & 1;
  const int lr = lane & 15, lh = lane >> 4;
  const int m0 = blockIdx.x << 7, n0 = blockIdx.y << 7;
  const int rA = lane >> 3;
  const int cA = (lane & 7) << 3;

  f32x4 acc[4][4];
  #pragma unroll
  for (int i = 0; i < 4; ++i)
    #pragma unroll
    for (int j = 0; j < 4; ++j) acc[i][j] = (f32x4)0.f;

  const int nkt = K >> 6;
  auto stage = [&](int kt){
    #pragma unroll
    for (int c = 0; c < 4; ++c){
      const int r = (c << 5) + (w << 3) + rA;
      gld16(A + (size_t)(m0 + r) * K + (kt << 6) + cA,
            (char*)As + ((c << 5) + (w << 3)) * 128);
      gld16(B + (size_t)(n0 + r) * K + (kt << 6) + cA,
            (char*)Bs + ((c << 5) + (w << 3)) * 128);
    }
  };
  stage(0);
  for (int kt = 0; kt < nkt; ++kt){
    __syncthreads();
    #pragma unroll
    for (int kk = 0; kk < 2; ++kk){
      bfx8 af[4], bg[4];
      #pragma unroll
      for (int i = 0; i < 4; ++i)
        af[i] = *(const bfx8*)(As + ((wm << 6) + (i << 4) + lr) * 64 + (kk << 5) + (lh << 3));
      #pragma unroll
      for (int j = 0; j < 4; ++j)
        bg[j] = *(const bfx8*)(Bs + ((wn << 6) + (j << 4) + lr) * 64 + (kk << 5) + (lh << 3));
      #pragma unroll
      for (int i = 0; i < 4; ++i)
        #pragma unroll
        for (int j = 0; j < 4; ++j)
          acc[i][j] = mfma16(af[i], bg[j], acc[i][j]);
    }
    __syncthreads();
    if (kt + 1 < nkt) stage(kt + 1);
  }
  #pragma unroll
  for (int i = 0; i < 4; ++i){
    const int row = m0 + (wm << 6) + (i << 4) + (lh << 2);
    #pragma unroll
    for (int j = 0; j < 4; ++j){
      const int col = n0 + (wn << 6) + (j << 4) + lr;
      if constexpr (MODE == 1){
        const float bv = bias ? bias[col] : 0.f;
        #pragma unroll
        for (int r = 0; r < 4; ++r){
          float v = acc[i][j][r] + bv;
          v = fmaxf(v, 0.f);
          Cb[(size_t)(row + r) * N + col] = f2bf(v);
        }
      } else if constexpr (MODE == 2){
        const float bv = bias ? bias[col] : 0.f;
        #pragma unroll
        for (int r = 0; r < 4; ++r){
          const size_t idx = (size_t)(row + r) * N + col;
          Cf[idx] += acc[i][j][r] + bv;
        }
      } else {
        const int br = col / 1536;
        const int rem = col - br * 1536;
        const int p = rem >> 9;
        const int c = rem & 511;
        const float bv = bias ? bias[(size_t)((br << 2) + p) * 512 + c] : 0.f;
        if (p < 2){
          #pragma unroll
          for (int r = 0; r < 4; ++r)
            qkp[((size_t)((br << 1) + p) * 8192 + row + r) * 512 + c] = f2bf(acc[i][j][r] + bv);
        } else {
          const int b_ = row >> 9, s0 = row & 511;
          const int hi = c >> 7, dk = c & 127;
          us4 pk;
          #pragma unroll
          for (int r = 0; r < 4; ++r) pk[r] = f2bf(acc[i][j][r] + bv);
          *(us4*)(vtp + (((size_t)(br * 16 + b_) * 4 + hi) * 128 + dk) * 512 + s0) = pk;
        }
      }
    }
  }
}

// ---------------------------------------------------------------- attention --
// 1D grid 1536 (XCD-swizzled). 4 waves; wave owns 16 q-rows. Full 512-wide
// score row in registers; bitpacked mask from LDS; K/V double-buffered in a
// unioned, XOR-swizzled LDS tile; P relayout via small wave-local LDS slice.
__global__ __launch_bounds__(256, 2)
void attn_kernel(const unsigned short* __restrict__ qk, const unsigned short* __restrict__ vt,
                 const unsigned* __restrict__ mp, unsigned short* __restrict__ outp)
{
  __shared__ unsigned short KV[2][4096];   // 8KB each: K tile [32][128] / V tile [128][32]
  __shared__ unsigned short Pl[4][16 * 40];// per-wave P slice, row stride 40 (80B, 16B-aligned)
  __shared__ unsigned Mk[64 * 17];         // packed mask words for this q-block
  const int tid = threadIdx.x;
  const int w = tid >> 6, lane = tid & 63;
  const int lr = lane & 15, lh = lane >> 4;
  // XCD swizzle: 8 q-tiles of one (br,bh) pair land on one XCD
  const int id = blockIdx.x;
  const int pair = (id & 7) * 192 / 8 + ((id >> 3) >> 3);
  const int qt = (id >> 3) & 7;
  const int br = pair >> 6, bh = pair & 63;
  const int b = bh >> 2, h = bh & 3;
  const int q0 = (qt << 6) + (w << 4);

  const unsigned short* qbase = qk + ((size_t)(br * 2 + 0) * 8192 + (size_t)b * 512) * 512 + h * 128;
  const unsigned short* kbase = qk + ((size_t)(br * 2 + 1) * 8192 + (size_t)b * 512) * 512 + h * 128;
  const unsigned short* vbase = vt + ((size_t)(br * 16 + b) * 4 + h) * 128 * 512;
  const unsigned* mrow = mp + ((size_t)br * 8192 + (size_t)b * 512 + (qt << 6)) * 16;

  // stage packed mask words: 64 rows x 16 words
  for (int idx = tid; idx < 1024; idx += 256){
    const int rw = idx >> 4, wd = idx & 15;
    Mk[rw * 17 + wd] = mrow[rw * 16 + wd];
  }

  bfx8 aq[4];
  #pragma unroll
  for (int t = 0; t < 4; ++t)
    aq[t] = *(const bfx8*)(qbase + (size_t)(q0 + lr) * 512 + (t << 5) + (lh << 3));

  f32x4 sc[16][2];
  const float scale = 0.08838834764831845f;  // 1/sqrt(128)

  // K staging: tile row trow (0..31), 16 slots/row; granule XOR (trow&7)
  auto stageK = [&](int kt){
    char* dst = (char*)KV[kt & 1];
    #pragma unroll
    for (int c2 = 0; c2 < 2; ++c2){
      const int trow = (c2 << 4) + (w << 2) + (lane >> 4);
      const int g = (lane & 15) ^ (trow & 7);
      gld16(kbase + (size_t)((kt << 5) + trow) * 512 + (g << 3),
            dst + ((c2 << 4) + (w << 2)) * 256);
    }
  };
  // V staging: tile row drow (0..127, = dk), 4 slots/row; granule XOR (drow&3)
  auto stageV = [&](int kt){
    char* dst = (char*)KV[kt & 1];
    #pragma unroll
    for (int c2 = 0; c2 < 2; ++c2){
      const int drow = (c2 << 6) + (w << 4) + (lane >> 2);
      const int g = (lane & 3) ^ (drow & 3);
      gld16(vbase + (size_t)drow * 512 + (kt << 5) + (g << 3),
            dst + ((c2 << 6) + (w << 4)) * 64);
    }
  };

  // phase 1: scores = QK^T, masked+scaled, in registers
  stageK(0);
  for (int kt = 0; kt < 16; ++kt){
    __syncthreads();
    if (kt < 15) stageK(kt + 1);
    const unsigned short* Ksb = KV[kt & 1];
    #pragma unroll
    for (int j = 0; j < 2; ++j){
      const int rk = (j << 4) + lr;
      f32x4 a2 = (f32x4)0.f;
      #pragma unroll
      for (int t = 0; t < 4; ++t){
        const int s = ((t << 2) + lh) ^ (rk & 7);
        bfx8 bk = *(const bfx8*)(Ksb + rk * 128 + (s << 3));
        a2 = mfma16(aq[t], bk, a2);
      }
      #pragma unroll
      for (int r = 0; r < 4; ++r){
        const int qloc = (w << 4) + (lh << 2) + r;
        const unsigned mword = Mk[qloc * 17 + kt];
        const int bit = (mword >> ((j << 4) + lr)) & 1;
        sc[kt][j][r] = bit ? -1e9f : a2[r] * scale;
      }
    }
  }

  // phase 2: wave-parallel softmax; sc becomes P (unnormalized)
  float mx[4] = {-3e38f, -3e38f, -3e38f, -3e38f};
  #pragma unroll
  for (int kt = 0; kt < 16; ++kt)
    #pragma unroll
    for (int j = 0; j < 2; ++j)
      #pragma unroll
      for (int r = 0; r < 4; ++r) mx[r] = fmaxf(mx[r], sc[kt][j][r]);
  #pragma unroll
  for (int s = 1; s < 16; s <<= 1)
    #pragma unroll
    for (int r = 0; r < 4; ++r) mx[r] = fmaxf(mx[r], __shfl_xor(mx[r], s, 64));
  float sm[4] = {0.f, 0.f, 0.f, 0.f};
  #pragma unroll
  for (int kt = 0; kt < 16; ++kt)
    #pragma unroll
    for (int j = 0; j < 2; ++j)
      #pragma unroll
      for (int r = 0; r < 4; ++r){
        const float pv = __expf(sc[kt][j][r] - mx[r]);
        sc[kt][j][r] = pv;
        sm[r] += pv;
      }
  #pragma unroll
  for (int s = 1; s < 16; s <<= 1)
    #pragma unroll
    for (int r = 0; r < 4; ++r) sm[r] += __shfl_xor(sm[r], s, 64);
  float linv[4];
  #pragma unroll
  for (int r = 0; r < 4; ++r) linv[r] = 1.f / sm[r];

  // phase 3: O = P * V  (V staged swizzled; P slice via wave-local LDS)
  f32x4 ao[8];
  #pragma unroll
  for (int j = 0; j < 8; ++j) ao[j] = (f32x4)0.f;
  unsigned short* pw = Pl[w];
  __syncthreads();          // all waves done reading K tiles before V reuses LDS
  stageV(0);
  for (int kt = 0; kt < 16; ++kt){
    __syncthreads();
    if (kt < 15) stageV(kt + 1);
    // write this kt's P slice (normalized, bf16), wave-local
    #pragma unroll
    for (int j = 0; j < 2; ++j)
      #pragma unroll
      for (int r = 0; r < 4; ++r)
        pw[((lh << 2) + r) * 40 + (j << 4) + lr] = f2bf(sc[kt][j][r] * linv[r]);
    bfx8 pa = *(const bfx8*)(pw + lr * 40 + (lh << 3));
    const unsigned short* Vsb = KV[kt & 1];
    #pragma unroll
    for (int j = 0; j < 8; ++j){
      const int dd = (j << 4) + lr;
      const int s = lh ^ (dd & 3);
      bfx8 bv = *(const bfx8*)(Vsb + dd * 32 + (s << 3));
      ao[j] = mfma16(pa, bv, ao[j]);
    }
  }
  const size_t obase = (size_t)(b * 512) * 1536 + br * 512 + h * 128;
  #pragma unroll
  for (int j = 0; j < 8; ++j){
    const int d = (j << 4) + lr;
    #pragma unroll
    for (int r = 0; r < 4; ++r){
      const int q = q0 + (lh << 2) + r;
      outp[obase + (size_t)q * 1536 + d] = f2bf(ao[j][r]);
    }
  }
}

// ---------------------------------------------------------------- out3 -------
__global__ __launch_bounds__(256, 4)
void out3_kernel(const unsigned short* __restrict__ t2, const float* __restrict__ w,
                 const float* __restrict__ b2, float* __restrict__ outp)
{
  const int row = (blockIdx.x << 2) + (threadIdx.x >> 6);
  const int lane = threadIdx.x & 63;
  const unsigned short* rp = t2 + (size_t)row * 256 + (lane << 2);
  float a0 = 0.f, a1 = 0.f;
  #pragma unroll
  for (int k = 0; k < 4; ++k){
    const float v = bf2f(rp[k]);
    const int kk = (lane << 2) + k;
    a0 += v * w[kk * 2 + 0];
    a1 += v * w[kk * 2 + 1];
  }
  #pragma unroll
  for (int s = 1; s < 64; s <<= 1){
    a0 += __shfl_xor(a0, s, 64);
    a1 += __shfl_xor(a1, s, 64);
  }
  if (lane == 0){
    outp[(size_t)row * 2 + 0] = a0 + b2[0];
    outp[(size_t)row * 2 + 1] = a1 + b2[1];
  }
}

// ---------------------------------------------------------------- launch -----
extern "C" void kernel_launch(void* const* d_in, const int* in_sizes, int n_in,
                              void* d_out, int out_size, void* d_ws, size_t ws_size,
                              hipStream_t stream)
{
  const float* x      = (const float*)d_in[0];
  const float* cond   = (const float*)d_in[1];
  const int*   mdoor  = (const int*)d_in[2];
  const int*   mself  = (const int*)d_in[3];
  const int*   mgen   = (const int*)d_in[4];
  const float* attn_w = (const float*)d_in[5];
  const float* attn_b = (const float*)d_in[6];
  const float* ff_w1  = (const float*)d_in[7];
  const float* ff_b1  = (const float*)d_in[8];
  const float* ff_w2  = (const float*)d_in[9];
  const float* ff_b2  = (const float*)d_in[10];
  const float* in_w   = (const float*)d_in[11];
  const float* in_b   = (const float*)d_in[12];
  const float* cond_w = (const float*)d_in[13];
  const float* cond_b = (const float*)d_in[14];
  const float* out1_w = (const float*)d_in[15];
  const float* out1_b = (const float*)d_in[16];
  const float* out2_w = (const float*)d_in[17];
  const float* out2_b = (const float*)d_in[18];
  const float* out3_w = (const float*)d_in[19];
  const float* out3_b = (const float*)d_in[20];

  char* p = (char*)d_ws;
  auto carve = [&](size_t bytes) -> char* {
    char* r = p; p += (bytes + 255) & ~(size_t)255; return r;
  };
  float*          h    = (float*)carve(8192ull * 512 * 4);
  unsigned short* h2   = (unsigned short*)carve(8192ull * 512 * 2);
  unsigned short* bqkv = (unsigned short*)carve(4ull * 4608 * 512 * 2);
  unsigned short* bout = (unsigned short*)carve(4ull * 512 * 1536 * 2);
  unsigned short* bff1 = (unsigned short*)carve(4ull * 1024 * 512 * 2);
  unsigned short* bff2 = (unsigned short*)carve(4ull * 512 * 1024 * 2);
  unsigned short* bo1  = (unsigned short*)carve(512ull * 512 * 2);
  unsigned short* bo2  = (unsigned short*)carve(256ull * 512 * 2);
  unsigned short* qkb  = (unsigned short*)carve(6ull * 8192 * 512 * 2);
  unsigned short* vtb  = (unsigned short*)carve(3ull * 16 * 4 * 128 * 512 * 2);
  unsigned short* att  = (unsigned short*)carve(8192ull * 1536 * 2);
  unsigned short* t    = (unsigned short*)carve(8192ull * 1024 * 2);
  unsigned short* t2   = (unsigned short*)carve(8192ull * 256 * 2);
  unsigned long long* mpk = (unsigned long long*)carve(24576ull * 8 * 8);
  float* outf = (float*)d_out;

  wconv_kernel<<<dim3(16, 16, 58), 256, 0, stream>>>(attn_w, ff_w1, ff_w2, out1_w, out2_w,
                                                     bqkv, bout, bff1, bff2, bo1, bo2);
  mpack_kernel<<<dim3(6144), 256, 0, stream>>>(mdoor, mself, mgen, mpk);
  embed_kernel<<<dim3(8192), 256, 0, stream>>>(x, cond, in_w, in_b, cond_w, cond_b, h);
  for (int l = 0; l < 4; ++l){
    inorm_kernel<<<dim3(2048), 256, 0, stream>>>(h, h2);
    gemm_bt<3><<<dim3(64, 36), 256, 0, stream>>>(h2, bqkv + (size_t)l * 4608 * 512,
        attn_b + (size_t)l * 6144, nullptr, nullptr, qkb, vtb, 8192, 4608, 512);
    attn_kernel<<<dim3(1536), 256, 0, stream>>>(qkb, vtb, (const unsigned*)mpk, att);
    gemm_bt<2><<<dim3(64, 4), 256, 0, stream>>>(att, bout + (size_t)l * 512 * 1536,
        nullptr, h, nullptr, nullptr, nullptr, 8192, 512, 1536);
    inorm_kernel<<<dim3(2048), 256, 0, stream>>>(h, h2);
    gemm_bt<1><<<dim3(64, 8), 256, 0, stream>>>(h2, bff1 + (size_t)l * 1024 * 512,
        ff_b1 + (size_t)l * 1024, nullptr, t, nullptr, nullptr, 8192, 1024, 512);
    gemm_bt<2><<<dim3(64, 4), 256, 0, stream>>>(t, bff2 + (size_t)l * 512 * 1024,
        ff_b2 + (size_t)l * 512, h, nullptr, nullptr, nullptr, 8192, 512, 1024);
  }
  f2b_kernel<<<dim3(4096), 256, 0, stream>>>(h, h2, 8192 * 512);
  gemm_bt<1><<<dim3(64, 4), 256, 0, stream>>>(h2, bo1, out1_b, nullptr, att, nullptr, nullptr, 8192, 512, 512);
  gemm_bt<1><<<dim3(64, 2), 256, 0, stream>>>(att, bo2, out2_b, nullptr, t2, nullptr, nullptr, 8192, 256, 512);
  out3_kernel<<<dim3(2048), 256, 0, stream>>>(t2, out3_w, out3_b, outf);
}